// Round 2
// baseline (85.887 us; speedup 1.0000x reference)
//
#include <hip/hip_runtime.h>
#include <math.h>

namespace {
constexpr int KB    = 16;        // spline bins
constexpr int OUTP  = 3*KB + 1;  // 49
constexpr int CDIM  = 64;
constexpr int HDIM  = 256;
constexpr int NCOL  = 1024;
constexpr int NROW  = 4096;
constexpr float BOUNDF = 5.0f;
constexpr float MBW_ = 0.001f;
constexpr float MBH_ = 0.001f;
constexpr float MD_  = 0.001f;
constexpr int PSTR = 83;  // 17 cumw + 16 widths + 17 cumh + 16 heights + 17 deriv
constexpr int RB   = 8;   // rows per block, layers 1&2
}

// ---------------------------------------------------------------------------
// Layer 1: h1 = relu(cond @ W1 + b1).  Thread owns hidden col j = tid.
// cond values are wave-uniform (row/col indices are blockIdx/loop derived)
// -> compiler emits s_load into SGPRs; fma = v_fmac(acc, s_cond, v_w1).
// ---------------------------------------------------------------------------
__global__ __launch_bounds__(256) void layer1_kernel(
    const float* __restrict__ cond,
    const float* __restrict__ W1, const float* __restrict__ b1,
    float* __restrict__ h1g)
{
    const int tid  = threadIdx.x;
    const int row0 = blockIdx.x * RB;

    float acc[RB];
    const float bb = b1[tid];
    #pragma unroll
    for (int r = 0; r < RB; ++r) acc[r] = bb;

    #pragma unroll 4
    for (int c4 = 0; c4 < CDIM/4; ++c4) {
        const float w0 = W1[(size_t)(c4*4+0)*HDIM + tid];
        const float w1 = W1[(size_t)(c4*4+1)*HDIM + tid];
        const float w2 = W1[(size_t)(c4*4+2)*HDIM + tid];
        const float w3 = W1[(size_t)(c4*4+3)*HDIM + tid];
        #pragma unroll
        for (int r = 0; r < RB; ++r) {
            const float4 cv = *(const float4*)(cond + (size_t)(row0+r)*CDIM + c4*4);
            acc[r] = fmaf(cv.x, w0, acc[r]);
            acc[r] = fmaf(cv.y, w1, acc[r]);
            acc[r] = fmaf(cv.z, w2, acc[r]);
            acc[r] = fmaf(cv.w, w3, acc[r]);
        }
    }
    #pragma unroll
    for (int r = 0; r < RB; ++r)
        h1g[(size_t)(row0+r)*HDIM + tid] = fmaxf(acc[r], 0.f);
}

// ---------------------------------------------------------------------------
// Layer 2: h2 = relu(h1 @ W2 + b2).  Same structure; the dominant GEMM
// (4096x256x256).  h1 operand via scalar loads (uniform), W2 via coalesced
// vector dwords reused across RB rows. Zero LDS in the hot loop.
// ---------------------------------------------------------------------------
__global__ __launch_bounds__(256) void layer2_kernel(
    const float* __restrict__ h1g,
    const float* __restrict__ W2, const float* __restrict__ b2,
    float* __restrict__ h2g)
{
    const int tid  = threadIdx.x;
    const int row0 = blockIdx.x * RB;

    float acc[RB];
    const float bb = b2[tid];
    #pragma unroll
    for (int r = 0; r < RB; ++r) acc[r] = bb;

    #pragma unroll 4
    for (int k4 = 0; k4 < HDIM/4; ++k4) {
        const float w0 = W2[(size_t)(k4*4+0)*HDIM + tid];
        const float w1 = W2[(size_t)(k4*4+1)*HDIM + tid];
        const float w2 = W2[(size_t)(k4*4+2)*HDIM + tid];
        const float w3 = W2[(size_t)(k4*4+3)*HDIM + tid];
        #pragma unroll
        for (int r = 0; r < RB; ++r) {
            const float4 hv = *(const float4*)(h1g + (size_t)(row0+r)*HDIM + k4*4);
            acc[r] = fmaf(hv.x, w0, acc[r]);
            acc[r] = fmaf(hv.y, w1, acc[r]);
            acc[r] = fmaf(hv.z, w2, acc[r]);
            acc[r] = fmaf(hv.w, w3, acc[r]);
        }
    }
    #pragma unroll
    for (int r = 0; r < RB; ++r)
        h2g[(size_t)(row0+r)*HDIM + tid] = fmaxf(acc[r], 0.f);
}

// ---------------------------------------------------------------------------
// Layer 3 + spline-parameter construction. One wave per 4 rows: lane o<49
// owns output unit o, W3 column chunk register-stationary, h2 via scalar
// loads. Then per-row softmax/cumsum/softplus (tiny serial tasks) -> params.
// ---------------------------------------------------------------------------
__global__ __launch_bounds__(256) void layer3_kernel(
    const float* __restrict__ h2g,
    const float* __restrict__ W3, const float* __restrict__ b3,
    float* __restrict__ params)
{
    const int tid  = threadIdx.x;
    const int lane = tid & 63;
    const int wid  = __builtin_amdgcn_readfirstlane(tid >> 6);  // wave id, forced SGPR
    const int row0 = blockIdx.x * 16 + wid * 4;                 // 16 rows/block

    __shared__ float p_s[16][OUTP];
    __shared__ float prm_s[16][PSTR];

    const int  o   = lane;
    const bool act = (o < OUTP);

    float acc[4];
    const float bb = act ? b3[o] : 0.f;
    #pragma unroll
    for (int r = 0; r < 4; ++r) acc[r] = bb;

    for (int k0 = 0; k0 < HDIM; k0 += 16) {
        float wv[16];
        #pragma unroll
        for (int i = 0; i < 16; ++i)
            wv[i] = act ? W3[(size_t)(k0+i)*OUTP + o] : 0.f;
        #pragma unroll
        for (int r = 0; r < 4; ++r) {
            const float* hrow = h2g + (size_t)(row0+r)*HDIM + k0;   // uniform -> s_load
            #pragma unroll
            for (int i = 0; i < 16; ++i)
                acc[r] = fmaf(hrow[i], wv[i], acc[r]);
        }
    }
    if (act) {
        #pragma unroll
        for (int r = 0; r < 4; ++r) p_s[wid*4 + r][o] = acc[r];
    }
    __syncthreads();

    // softmax+cumsum (widths, heights) and softplus (derivs): 16 rows x 3 segs
    if (tid < 16*3) {
        const int r   = tid / 3;
        const int seg = tid - 3*r;
        if (seg < 2) {
            const int   off   = (seg == 0) ? 0  : KB;
            const int   cbase = (seg == 0) ? 0  : 33;
            const int   wbase = (seg == 0) ? 17 : 50;
            const float mb    = (seg == 0) ? MBW_ : MBH_;
            float m = -1e30f;
            #pragma unroll
            for (int i = 0; i < KB; ++i) m = fmaxf(m, p_s[r][off+i]);
            float e[KB];
            float s = 0.f;
            #pragma unroll
            for (int i = 0; i < KB; ++i) { e[i] = expf(p_s[r][off+i] - m); s += e[i]; }
            const float span = (2.f*BOUNDF - (float)KB*mb) / s;
            float c = -BOUNDF;
            prm_s[r][cbase] = c;
            #pragma unroll
            for (int i = 0; i < KB; ++i) {
                const float w = mb + span*e[i];
                prm_s[r][wbase + i] = w;
                c += w;
                prm_s[r][cbase + 1 + i] = c;
            }
        } else {
            #pragma unroll
            for (int i = 0; i < KB+1; ++i) {
                const float x  = p_s[r][2*KB + i];
                const float sp = (x > 20.f) ? x : log1pf(expf(x));
                prm_s[r][66 + i] = MD_ + sp;
            }
        }
    }
    __syncthreads();

    for (int i = tid; i < 16*PSTR; i += 256)
        params[(size_t)blockIdx.x*16*PSTR + i] = (&prm_s[0][0])[i];
}

// ---------------------------------------------------------------------------
// Spline application: one block per row, float4 I/O (16B/lane).
// ---------------------------------------------------------------------------
__global__ __launch_bounds__(256) void spline_kernel(
    const float* __restrict__ y,
    const float* __restrict__ params,
    float* __restrict__ out,
    float* __restrict__ logdet)
{
    __shared__ float prm[PSTR];
    const int b   = blockIdx.x;
    const int tid = threadIdx.x;
    if (tid < PSTR) prm[tid] = params[(size_t)b*PSTR + tid];
    __syncthreads();

    const float* cumw    = prm;
    const float* widths  = prm + 17;
    const float* cumh    = prm + 33;
    const float* heights = prm + 50;
    const float* deriv   = prm + 66;

    float cw[KB];
    #pragma unroll
    for (int k = 0; k < KB; ++k) cw[k] = cumw[k+1];

    const int    n0   = tid * 4;
    const size_t base = (size_t)b * NCOL + n0;
    const float4 yv   = *(const float4*)(y + base);
    const float  yy[4] = {yv.x, yv.y, yv.z, yv.w};
    float ov[4], lv[4];

    #pragma unroll
    for (int i = 0; i < 4; ++i) {
        const float yi = yy[i];
        const bool outside = (yi < -BOUNDF) || (yi > BOUNDF);
        const float xc = fminf(fmaxf(yi, -BOUNDF), BOUNDF);
        int bin = 0;
        #pragma unroll
        for (int k = 0; k < KB; ++k) bin += (xc >= cw[k]) ? 1 : 0;
        bin = min(bin, KB-1);

        const float x0 = cumw[bin];
        const float w  = widths[bin];
        const float y0 = cumh[bin];
        const float hh = heights[bin];
        const float d0 = deriv[bin];
        const float d1 = deriv[bin+1];

        const float delta = hh / w;
        const float theta = (xc - x0) / w;
        const float omt   = 1.f - theta;
        const float tt    = theta * theta;
        const float tomt  = theta * omt;
        const float num   = hh * (delta*tt + d0*tomt);
        const float den   = delta + (d0 + d1 - 2.f*delta)*tomt;
        const float o     = y0 + num/den;
        const float der_num = fmaxf(delta*delta*(d1*tt + 2.f*delta*tomt + d0*omt*omt), 1e-12f);
        const float der_den = fmaxf(den*den, 1e-12f);
        const float ld      = logf(der_num) - logf(der_den);

        ov[i] = outside ? yi : o;
        lv[i] = outside ? 0.f : ld;
    }

    *(float4*)(out + base)    = make_float4(ov[0], ov[1], ov[2], ov[3]);
    *(float4*)(logdet + base) = make_float4(lv[0], lv[1], lv[2], lv[3]);
}

extern "C" void kernel_launch(void* const* d_in, const int* in_sizes, int n_in,
                              void* d_out, int out_size, void* d_ws, size_t ws_size,
                              hipStream_t stream) {
    const float* cond = (const float*)d_in[0];
    const float* y    = (const float*)d_in[1];
    const float* W1   = (const float*)d_in[2];
    const float* b1   = (const float*)d_in[3];
    const float* W2   = (const float*)d_in[4];
    const float* b2   = (const float*)d_in[5];
    const float* W3   = (const float*)d_in[6];
    const float* b3   = (const float*)d_in[7];

    float* out    = (float*)d_out;
    float* logdet = out + (size_t)NROW * NCOL;

    // Scratch plan: params (1.36 MB) in d_ws; h1/h2 (4 MB each) borrow the
    // d_out region, which is only written (fully) by the final spline kernel.
    float* params = (float*)d_ws;
    float* h1g    = out;                              // 4096*256 floats
    float* h2g    = out + (size_t)NROW * HDIM;        // next 4096*256 floats

    layer1_kernel<<<NROW/RB, 256, 0, stream>>>(cond, W1, b1, h1g);
    layer2_kernel<<<NROW/RB, 256, 0, stream>>>(h1g, W2, b2, h2g);
    layer3_kernel<<<NROW/16, 256, 0, stream>>>(h2g, W3, b3, params);
    spline_kernel<<<NROW, 256, 0, stream>>>(y, params, out, logdet);
}

// Round 3
// 47.579 us; speedup vs baseline: 1.8052x; 1.8052x over previous
//
#include <hip/hip_runtime.h>
#include <math.h>

namespace {
constexpr int KB    = 16;        // spline bins
constexpr int OUTP  = 3*KB + 1;  // 49
constexpr int CDIM  = 64;
constexpr int HDIM  = 256;
constexpr int NCOL  = 1024;
constexpr int NROW  = 4096;
constexpr float BOUNDF = 5.0f;
constexpr float MBW_ = 0.001f;
constexpr float MBH_ = 0.001f;
constexpr float MD_  = 0.001f;
constexpr int PSTR = 51;  // 17 cumw + 17 cumh + 17 deriv (widths/heights by differencing)
constexpr int NR   = 8;   // rows per block
}

// ---------------------------------------------------------------------------
// Fused MLP -> spline params. One block = 8 rows, 256 threads = 4 waves.
// Split-K: wave w owns K-slice; lane owns 4 consecutive cols (float4 W loads,
// W read once per block). Broadcast activations via per-slice ds_read_b128
// (4x fewer LDS instrs than all-waves-all-K). Cross-wave partials through
// ps[4][8][256]: b128 writes lane-contiguous, b32 reads stride-1 (both
// conflict-free).
// ---------------------------------------------------------------------------
__global__ __launch_bounds__(256, 2) void mlp_kernel(
    const float* __restrict__ cond,
    const float* __restrict__ W1, const float* __restrict__ b1,
    const float* __restrict__ W2, const float* __restrict__ b2,
    const float* __restrict__ W3, const float* __restrict__ b3,
    float* __restrict__ params)
{
    __shared__ float cond_s[NR][CDIM];       //  2 KB
    __shared__ float ps[4][NR][HDIM];        // 32 KB cross-wave partials
    __shared__ float h_s[2][NR][HDIM];       // 16 KB h1, h2
    __shared__ float p_s[NR][OUTP];          //  1.6 KB
    __shared__ float prm_s[NR][PSTR];        //  1.6 KB

    const int tid  = threadIdx.x;
    const int lane = tid & 63;
    const int wid  = tid >> 6;
    const int row0 = blockIdx.x * NR;

    // stage cond rows (coalesced)
    for (int i = tid; i < NR*CDIM; i += 256)
        (&cond_s[0][0])[i] = cond[(size_t)row0*CDIM + i];
    __syncthreads();

    // ---- layer 1: h1 = relu(cond @ W1 + b1); wave wid owns k in [16w,16w+16)
    {
        float acc[NR][4];
        #pragma unroll
        for (int r = 0; r < NR; ++r)
            #pragma unroll
            for (int c = 0; c < 4; ++c) acc[r][c] = 0.f;

        #pragma unroll
        for (int kg = 0; kg < 4; ++kg) {               // 4 k per tile
            const int k0 = 16*wid + 4*kg;
            float4 wv[4];
            #pragma unroll
            for (int kk = 0; kk < 4; ++kk)
                wv[kk] = *(const float4*)(W1 + (size_t)(k0+kk)*HDIM + 4*lane);
            #pragma unroll
            for (int r = 0; r < NR; ++r) {
                const float4 cv = *(const float4*)&cond_s[r][k0];  // uniform -> broadcast
                acc[r][0] = fmaf(cv.x, wv[0].x, acc[r][0]);
                acc[r][1] = fmaf(cv.x, wv[0].y, acc[r][1]);
                acc[r][2] = fmaf(cv.x, wv[0].z, acc[r][2]);
                acc[r][3] = fmaf(cv.x, wv[0].w, acc[r][3]);
                acc[r][0] = fmaf(cv.y, wv[1].x, acc[r][0]);
                acc[r][1] = fmaf(cv.y, wv[1].y, acc[r][1]);
                acc[r][2] = fmaf(cv.y, wv[1].z, acc[r][2]);
                acc[r][3] = fmaf(cv.y, wv[1].w, acc[r][3]);
                acc[r][0] = fmaf(cv.z, wv[2].x, acc[r][0]);
                acc[r][1] = fmaf(cv.z, wv[2].y, acc[r][1]);
                acc[r][2] = fmaf(cv.z, wv[2].z, acc[r][2]);
                acc[r][3] = fmaf(cv.z, wv[2].w, acc[r][3]);
                acc[r][0] = fmaf(cv.w, wv[3].x, acc[r][0]);
                acc[r][1] = fmaf(cv.w, wv[3].y, acc[r][1]);
                acc[r][2] = fmaf(cv.w, wv[3].z, acc[r][2]);
                acc[r][3] = fmaf(cv.w, wv[3].w, acc[r][3]);
            }
        }
        #pragma unroll
        for (int r = 0; r < NR; ++r)
            *(float4*)&ps[wid][r][4*lane] = make_float4(acc[r][0], acc[r][1], acc[r][2], acc[r][3]);
    }
    __syncthreads();
    {   // reduce partials -> h1
        const float bb = b1[tid];
        #pragma unroll
        for (int r = 0; r < NR; ++r) {
            const float s = ps[0][r][tid] + ps[1][r][tid] + ps[2][r][tid] + ps[3][r][tid];
            h_s[0][r][tid] = fmaxf(s + bb, 0.f);
        }
    }
    __syncthreads();

    // ---- layer 2: h2 = relu(h1 @ W2 + b2); wave wid owns k in [64w,64w+64)
    {
        float acc[NR][4];
        #pragma unroll
        for (int r = 0; r < NR; ++r)
            #pragma unroll
            for (int c = 0; c < 4; ++c) acc[r][c] = 0.f;

        #pragma unroll 2
        for (int kg = 0; kg < 16; ++kg) {
            const int k0 = 64*wid + 4*kg;
            float4 wv[4];
            #pragma unroll
            for (int kk = 0; kk < 4; ++kk)
                wv[kk] = *(const float4*)(W2 + (size_t)(k0+kk)*HDIM + 4*lane);
            #pragma unroll
            for (int r = 0; r < NR; ++r) {
                const float4 hv = *(const float4*)&h_s[0][r][k0];  // uniform -> broadcast
                acc[r][0] = fmaf(hv.x, wv[0].x, acc[r][0]);
                acc[r][1] = fmaf(hv.x, wv[0].y, acc[r][1]);
                acc[r][2] = fmaf(hv.x, wv[0].z, acc[r][2]);
                acc[r][3] = fmaf(hv.x, wv[0].w, acc[r][3]);
                acc[r][0] = fmaf(hv.y, wv[1].x, acc[r][0]);
                acc[r][1] = fmaf(hv.y, wv[1].y, acc[r][1]);
                acc[r][2] = fmaf(hv.y, wv[1].z, acc[r][2]);
                acc[r][3] = fmaf(hv.y, wv[1].w, acc[r][3]);
                acc[r][0] = fmaf(hv.z, wv[2].x, acc[r][0]);
                acc[r][1] = fmaf(hv.z, wv[2].y, acc[r][1]);
                acc[r][2] = fmaf(hv.z, wv[2].z, acc[r][2]);
                acc[r][3] = fmaf(hv.z, wv[2].w, acc[r][3]);
                acc[r][0] = fmaf(hv.w, wv[3].x, acc[r][0]);
                acc[r][1] = fmaf(hv.w, wv[3].y, acc[r][1]);
                acc[r][2] = fmaf(hv.w, wv[3].z, acc[r][2]);
                acc[r][3] = fmaf(hv.w, wv[3].w, acc[r][3]);
            }
        }
        #pragma unroll
        for (int r = 0; r < NR; ++r)
            *(float4*)&ps[wid][r][4*lane] = make_float4(acc[r][0], acc[r][1], acc[r][2], acc[r][3]);
    }
    __syncthreads();
    {   // reduce partials -> h2
        const float bb = b2[tid];
        #pragma unroll
        for (int r = 0; r < NR; ++r) {
            const float s = ps[0][r][tid] + ps[1][r][tid] + ps[2][r][tid] + ps[3][r][tid];
            h_s[1][r][tid] = fmaxf(s + bb, 0.f);
        }
    }
    __syncthreads();

    // ---- layer 3: p = h2 @ W3 + b3; wave wid owns k-slice, lane = output unit
    {
        const int  o   = lane;
        const bool act = (o < OUTP);
        float acc[NR];
        #pragma unroll
        for (int r = 0; r < NR; ++r) acc[r] = 0.f;

        #pragma unroll 4
        for (int kg = 0; kg < 16; ++kg) {
            const int k0 = 64*wid + 4*kg;
            float wv[4];
            #pragma unroll
            for (int kk = 0; kk < 4; ++kk)
                wv[kk] = act ? W3[(size_t)(k0+kk)*OUTP + o] : 0.f;
            #pragma unroll
            for (int r = 0; r < NR; ++r) {
                const float4 hv = *(const float4*)&h_s[1][r][k0];  // uniform -> broadcast
                acc[r] = fmaf(hv.x, wv[0], acc[r]);
                acc[r] = fmaf(hv.y, wv[1], acc[r]);
                acc[r] = fmaf(hv.z, wv[2], acc[r]);
                acc[r] = fmaf(hv.w, wv[3], acc[r]);
            }
        }
        if (act) {
            #pragma unroll
            for (int r = 0; r < NR; ++r) ps[wid][r][o] = acc[r];
        }
    }
    __syncthreads();
    // reduce layer-3 partials
    for (int t = tid; t < NR*OUTP; t += 256) {
        const int r = t / OUTP;
        const int o = t - r*OUTP;
        p_s[r][o] = ps[0][r][o] + ps[1][r][o] + ps[2][r][o] + ps[3][r][o] + b3[o];
    }
    __syncthreads();

    // ---- softmax+cumsum (widths, heights) and softplus (derivs)
    if (tid < NR*3) {
        const int r   = tid / 3;
        const int seg = tid - 3*r;
        if (seg < 2) {
            const int   off   = (seg == 0) ? 0 : KB;
            const int   cbase = (seg == 0) ? 0 : 17;
            const float mb    = (seg == 0) ? MBW_ : MBH_;
            float m = -1e30f;
            #pragma unroll
            for (int i = 0; i < KB; ++i) m = fmaxf(m, p_s[r][off+i]);
            float e[KB];
            float s = 0.f;
            #pragma unroll
            for (int i = 0; i < KB; ++i) { e[i] = expf(p_s[r][off+i] - m); s += e[i]; }
            const float span = (2.f*BOUNDF - (float)KB*mb) / s;
            float c = -BOUNDF;
            prm_s[r][cbase] = c;
            #pragma unroll
            for (int i = 0; i < KB; ++i) {
                c += mb + span*e[i];
                prm_s[r][cbase + 1 + i] = c;
            }
        } else {
            #pragma unroll
            for (int i = 0; i < KB+1; ++i) {
                const float x  = p_s[r][2*KB + i];
                const float sp = (x > 20.f) ? x : log1pf(expf(x));
                prm_s[r][34 + i] = MD_ + sp;
            }
        }
    }
    __syncthreads();

    // coalesced dump (NR*51 contiguous floats)
    for (int i = tid; i < NR*PSTR; i += 256)
        params[(size_t)row0*PSTR + i] = (&prm_s[0][0])[i];
}

// ---------------------------------------------------------------------------
// Spline application: one block per row, float4 I/O; adjacent-pair gathers
// (cumw/cumh/deriv) so the compiler can fuse into ds_read2_b32.
// ---------------------------------------------------------------------------
__global__ __launch_bounds__(256) void spline_kernel(
    const float* __restrict__ y,
    const float* __restrict__ params,
    float* __restrict__ out,
    float* __restrict__ logdet)
{
    __shared__ float prm[PSTR];
    const int b   = blockIdx.x;
    const int tid = threadIdx.x;
    if (tid < PSTR) prm[tid] = params[(size_t)b*PSTR + tid];
    __syncthreads();

    const float* cumw  = prm;        // 17
    const float* cumh  = prm + 17;   // 17
    const float* deriv = prm + 34;   // 17

    float cw[KB];
    #pragma unroll
    for (int k = 0; k < KB; ++k) cw[k] = cumw[k+1];

    const size_t base = (size_t)b * NCOL + tid * 4;
    const float4 yv   = *(const float4*)(y + base);
    const float  yy[4] = {yv.x, yv.y, yv.z, yv.w};
    float ov[4], lv[4];

    #pragma unroll
    for (int i = 0; i < 4; ++i) {
        const float yi = yy[i];
        const bool outside = (yi < -BOUNDF) || (yi > BOUNDF);
        const float xc = fminf(fmaxf(yi, -BOUNDF), BOUNDF);
        int bin = 0;
        #pragma unroll
        for (int k = 0; k < KB; ++k) bin += (xc >= cw[k]) ? 1 : 0;
        bin = min(bin, KB-1);

        const float c0 = cumw[bin],  c1 = cumw[bin+1];    // pair -> ds_read2
        const float g0 = cumh[bin],  g1 = cumh[bin+1];
        const float d0 = deriv[bin], d1 = deriv[bin+1];
        const float w  = c1 - c0;
        const float hh = g1 - g0;

        const float delta = hh / w;
        const float theta = (xc - c0) / w;
        const float omt   = 1.f - theta;
        const float tt    = theta * theta;
        const float tomt  = theta * omt;
        const float num   = hh * (delta*tt + d0*tomt);
        const float den   = delta + (d0 + d1 - 2.f*delta)*tomt;
        const float o     = g0 + num/den;
        const float der_num = fmaxf(delta*delta*(d1*tt + 2.f*delta*tomt + d0*omt*omt), 1e-12f);
        const float der_den = fmaxf(den*den, 1e-12f);
        const float ld      = logf(der_num) - logf(der_den);

        ov[i] = outside ? yi : o;
        lv[i] = outside ? 0.f : ld;
    }

    *(float4*)(out + base)    = make_float4(ov[0], ov[1], ov[2], ov[3]);
    *(float4*)(logdet + base) = make_float4(lv[0], lv[1], lv[2], lv[3]);
}

extern "C" void kernel_launch(void* const* d_in, const int* in_sizes, int n_in,
                              void* d_out, int out_size, void* d_ws, size_t ws_size,
                              hipStream_t stream) {
    const float* cond = (const float*)d_in[0];
    const float* y    = (const float*)d_in[1];
    const float* W1   = (const float*)d_in[2];
    const float* b1   = (const float*)d_in[3];
    const float* W2   = (const float*)d_in[4];
    const float* b2   = (const float*)d_in[5];
    const float* W3   = (const float*)d_in[6];
    const float* b3   = (const float*)d_in[7];

    float* out    = (float*)d_out;
    float* logdet = out + (size_t)NROW * NCOL;
    float* params = (float*)d_ws;   // NROW * 51 floats = 0.84 MB

    mlp_kernel<<<NROW/NR, 256, 0, stream>>>(cond, W1, b1, W2, b2, W3, b3, params);
    spline_kernel<<<NROW, 256, 0, stream>>>(y, params, out, logdet);
}

// Round 4
// 43.293 us; speedup vs baseline: 1.9838x; 1.0990x over previous
//
#include <hip/hip_runtime.h>
#include <math.h>

namespace {
constexpr int KB    = 16;        // spline bins
constexpr int OUTP  = 3*KB + 1;  // 49
constexpr int CDIM  = 64;
constexpr int HDIM  = 256;
constexpr int NCOL  = 1024;
constexpr int NROW  = 4096;
constexpr float BOUNDF = 5.0f;
constexpr float MBW_ = 0.001f;
constexpr float MBH_ = 0.001f;
constexpr float MD_  = 0.001f;
constexpr int NR   = 8;   // rows per block
}

// ---------------------------------------------------------------------------
// Fully fused: MLP -> spline params (LDS) -> spline application for NR rows.
// 512 blocks x 256 threads (4 waves). Split-K MLP (wave owns K-slice, lane
// owns 4 consecutive cols -> coalesced float4 W loads, register-prefetched).
// Spline phase streams 8 rows of y with 8 outstanding float4 loads/thread,
// gathers bin params from packed 32B LDS records (1 b128 + 1 b64 per elem).
// ---------------------------------------------------------------------------
__global__ __launch_bounds__(256, 2) void fused_spline_flow_kernel(
    const float* __restrict__ cond,
    const float* __restrict__ y,
    const float* __restrict__ W1, const float* __restrict__ b1,
    const float* __restrict__ W2, const float* __restrict__ b2,
    const float* __restrict__ W3, const float* __restrict__ b3,
    float* __restrict__ out, float* __restrict__ logdet)
{
    __shared__ float cond_s[NR][CDIM];       //  2   KB
    __shared__ float ps[4][NR][HDIM];        // 32   KB cross-wave partials
    __shared__ float h_s[NR][HDIM];          //  8   KB h1 then h2 (reused)
    __shared__ float p_s[NR][OUTP];          //  1.6 KB
    __shared__ float prm_s[NR][51];          //  1.6 KB cumw|cumh|deriv (17 each)
    __shared__ float scan_s[NR][16];         //  0.5 KB thresholds cumw[1..16]
    __shared__ float rec[NR][KB][8];         //  4   KB packed 32B bin records

    const int tid  = threadIdx.x;
    const int lane = tid & 63;
    const int wid  = tid >> 6;
    const int row0 = blockIdx.x * NR;

    // ---- stage cond rows (float4 coalesced)
    if (tid < NR*CDIM/4)
        *((float4*)&cond_s[0][0] + tid) = *((const float4*)(cond + (size_t)row0*CDIM) + tid);
    __syncthreads();

    // ---- layer 1: h1 = relu(cond @ W1 + b1); wave owns k in [16w, 16w+16)
    {
        float acc[NR][4];
        #pragma unroll
        for (int r = 0; r < NR; ++r)
            #pragma unroll
            for (int c = 0; c < 4; ++c) acc[r][c] = 0.f;

        #pragma unroll
        for (int kg = 0; kg < 4; ++kg) {
            const int k0 = 16*wid + 4*kg;
            float4 wv[4];
            #pragma unroll
            for (int kk = 0; kk < 4; ++kk)
                wv[kk] = *(const float4*)(W1 + (size_t)(k0+kk)*HDIM + 4*lane);
            #pragma unroll
            for (int r = 0; r < NR; ++r) {
                const float4 cv4 = *(const float4*)&cond_s[r][k0];
                const float cv[4] = {cv4.x, cv4.y, cv4.z, cv4.w};
                const float wf[4][4] = {{wv[0].x,wv[0].y,wv[0].z,wv[0].w},
                                        {wv[1].x,wv[1].y,wv[1].z,wv[1].w},
                                        {wv[2].x,wv[2].y,wv[2].z,wv[2].w},
                                        {wv[3].x,wv[3].y,wv[3].z,wv[3].w}};
                #pragma unroll
                for (int kk = 0; kk < 4; ++kk)
                    #pragma unroll
                    for (int c = 0; c < 4; ++c)
                        acc[r][c] = fmaf(cv[kk], wf[kk][c], acc[r][c]);
            }
        }
        #pragma unroll
        for (int r = 0; r < NR; ++r)
            *(float4*)&ps[wid][r][4*lane] = make_float4(acc[r][0], acc[r][1], acc[r][2], acc[r][3]);
    }
    __syncthreads();
    {   // reduce partials -> h1
        const float bb = b1[tid];
        #pragma unroll
        for (int r = 0; r < NR; ++r)
            h_s[r][tid] = fmaxf(ps[0][r][tid] + ps[1][r][tid] + ps[2][r][tid] + ps[3][r][tid] + bb, 0.f);
    }
    __syncthreads();

    // ---- layer 2: h2 = relu(h1 @ W2 + b2); wave owns k in [64w, 64w+64)
    {
        float acc[NR][4];
        #pragma unroll
        for (int r = 0; r < NR; ++r)
            #pragma unroll
            for (int c = 0; c < 4; ++c) acc[r][c] = 0.f;

        float4 wn[4];
        #pragma unroll
        for (int kk = 0; kk < 4; ++kk)
            wn[kk] = *(const float4*)(W2 + (size_t)(64*wid+kk)*HDIM + 4*lane);

        #pragma unroll 2
        for (int kg = 0; kg < 16; ++kg) {
            const int k0 = 64*wid + 4*kg;
            float4 wv[4];
            #pragma unroll
            for (int kk = 0; kk < 4; ++kk) wv[kk] = wn[kk];
            if (kg < 15) {
                #pragma unroll
                for (int kk = 0; kk < 4; ++kk)
                    wn[kk] = *(const float4*)(W2 + (size_t)(k0+4+kk)*HDIM + 4*lane);
            }
            #pragma unroll
            for (int r = 0; r < NR; ++r) {
                const float4 hv4 = *(const float4*)&h_s[r][k0];
                const float hv[4] = {hv4.x, hv4.y, hv4.z, hv4.w};
                const float wf[4][4] = {{wv[0].x,wv[0].y,wv[0].z,wv[0].w},
                                        {wv[1].x,wv[1].y,wv[1].z,wv[1].w},
                                        {wv[2].x,wv[2].y,wv[2].z,wv[2].w},
                                        {wv[3].x,wv[3].y,wv[3].z,wv[3].w}};
                #pragma unroll
                for (int kk = 0; kk < 4; ++kk)
                    #pragma unroll
                    for (int c = 0; c < 4; ++c)
                        acc[r][c] = fmaf(hv[kk], wf[kk][c], acc[r][c]);
            }
        }
        #pragma unroll
        for (int r = 0; r < NR; ++r)
            *(float4*)&ps[wid][r][4*lane] = make_float4(acc[r][0], acc[r][1], acc[r][2], acc[r][3]);
    }
    __syncthreads();
    {   // reduce partials -> h2 (overwrite h_s; all h1 reads completed pre-barrier)
        const float bb = b2[tid];
        #pragma unroll
        for (int r = 0; r < NR; ++r)
            h_s[r][tid] = fmaxf(ps[0][r][tid] + ps[1][r][tid] + ps[2][r][tid] + ps[3][r][tid] + bb, 0.f);
    }
    __syncthreads();

    // ---- layer 3: p = h2 @ W3 + b3; lane = output unit, wave owns k-slice
    {
        const int  o   = lane;
        const bool act = (o < OUTP);
        float acc[NR];
        #pragma unroll
        for (int r = 0; r < NR; ++r) acc[r] = 0.f;

        #pragma unroll 4
        for (int kg = 0; kg < 16; ++kg) {
            const int k0 = 64*wid + 4*kg;
            float wv[4];
            #pragma unroll
            for (int kk = 0; kk < 4; ++kk)
                wv[kk] = act ? W3[(size_t)(k0+kk)*OUTP + o] : 0.f;
            #pragma unroll
            for (int r = 0; r < NR; ++r) {
                const float4 hv = *(const float4*)&h_s[r][k0];
                acc[r] = fmaf(hv.x, wv[0], acc[r]);
                acc[r] = fmaf(hv.y, wv[1], acc[r]);
                acc[r] = fmaf(hv.z, wv[2], acc[r]);
                acc[r] = fmaf(hv.w, wv[3], acc[r]);
            }
        }
        if (act) {
            #pragma unroll
            for (int r = 0; r < NR; ++r) ps[wid][r][o] = acc[r];
        }
    }
    __syncthreads();
    for (int t = tid; t < NR*OUTP; t += 256) {
        const int r = t / OUTP;
        const int o = t - r*OUTP;
        p_s[r][o] = ps[0][r][o] + ps[1][r][o] + ps[2][r][o] + ps[3][r][o] + b3[o];
    }
    __syncthreads();

    // ---- softmax+cumsum (widths, heights) and softplus (derivs)
    if (tid < NR*3) {
        const int r   = tid / 3;
        const int seg = tid - 3*r;
        if (seg < 2) {
            const int   off   = (seg == 0) ? 0 : KB;
            const int   cbase = (seg == 0) ? 0 : 17;
            const float mb    = (seg == 0) ? MBW_ : MBH_;
            float m = -1e30f;
            #pragma unroll
            for (int i = 0; i < KB; ++i) m = fmaxf(m, p_s[r][off+i]);
            float e[KB];
            float s = 0.f;
            #pragma unroll
            for (int i = 0; i < KB; ++i) { e[i] = __expf(p_s[r][off+i] - m); s += e[i]; }
            const float span = (2.f*BOUNDF - (float)KB*mb) / s;
            float c = -BOUNDF;
            prm_s[r][cbase] = c;
            #pragma unroll
            for (int i = 0; i < KB; ++i) {
                c += mb + span*e[i];
                prm_s[r][cbase + 1 + i] = c;
            }
        } else {
            #pragma unroll
            for (int i = 0; i < KB+1; ++i) {
                const float x  = p_s[r][2*KB + i];
                const float sp = (x > 20.f) ? x : __logf(1.f + __expf(x));
                prm_s[r][34 + i] = MD_ + sp;
            }
        }
    }
    __syncthreads();

    // ---- build packed 32B per-bin records + scan thresholds
    if (tid < NR*KB) {
        const int r = tid >> 4;
        const int k = tid & 15;
        rec[r][k][0] = prm_s[r][k];          // cumw[k]
        rec[r][k][1] = prm_s[r][k+1];        // cumw[k+1]
        rec[r][k][2] = prm_s[r][17+k];       // cumh[k]
        rec[r][k][3] = prm_s[r][17+k+1];     // cumh[k+1]
        rec[r][k][4] = prm_s[r][34+k];       // deriv[k]
        rec[r][k][5] = prm_s[r][34+k+1];     // deriv[k+1]
        rec[r][k][6] = 0.f; rec[r][k][7] = 0.f;
        scan_s[r][k] = prm_s[r][k+1];        // cumw[1..16]
    }
    __syncthreads();

    // ---- spline application: 8 rows, thread owns cols [4t, 4t+4)
    float4 yv[NR];
    #pragma unroll
    for (int e = 0; e < NR; ++e)   // 8 outstanding loads -> BW-friendly
        yv[e] = *(const float4*)(y + (size_t)(row0+e)*NCOL + 4*tid);

    #pragma unroll 2
    for (int e = 0; e < NR; ++e) {
        float cw[KB];
        #pragma unroll
        for (int q = 0; q < 4; ++q) {
            const float4 t4 = *(const float4*)&scan_s[e][4*q];
            cw[4*q+0] = t4.x; cw[4*q+1] = t4.y; cw[4*q+2] = t4.z; cw[4*q+3] = t4.w;
        }
        const float yy[4] = {yv[e].x, yv[e].y, yv[e].z, yv[e].w};
        float ov[4], lv[4];
        #pragma unroll
        for (int i = 0; i < 4; ++i) {
            const float yi = yy[i];
            const bool outside = (yi < -BOUNDF) || (yi > BOUNDF);
            const float xc = fminf(fmaxf(yi, -BOUNDF), BOUNDF);
            int bin = 0;
            #pragma unroll
            for (int k = 0; k < KB; ++k) bin += (xc >= cw[k]) ? 1 : 0;
            bin = min(bin, KB-1);

            const float4 lo = *(const float4*)&rec[e][bin][0];  // ds_read_b128
            const float2 hi = *(const float2*)&rec[e][bin][4];  // ds_read_b64
            const float w  = lo.y - lo.x;
            const float hh = lo.w - lo.z;
            const float d0 = hi.x, d1 = hi.y;

            const float inv_w = __fdividef(1.f, w);
            const float delta = hh * inv_w;
            const float theta = (xc - lo.x) * inv_w;
            const float omt   = 1.f - theta;
            const float tt    = theta * theta;
            const float tomt  = theta * omt;
            const float num   = hh * (delta*tt + d0*tomt);
            const float den   = delta + (d0 + d1 - 2.f*delta)*tomt;
            const float o     = lo.z + __fdividef(num, den);
            const float der_num = fmaxf(delta*delta*(d1*tt + 2.f*delta*tomt + d0*omt*omt), 1e-12f);
            const float der_den = fmaxf(den*den, 1e-12f);
            const float ld      = __logf(__fdividef(der_num, der_den));

            ov[i] = outside ? yi : o;
            lv[i] = outside ? 0.f : ld;
        }
        const size_t base = (size_t)(row0+e) * NCOL + 4*tid;
        *(float4*)(out + base)    = make_float4(ov[0], ov[1], ov[2], ov[3]);
        *(float4*)(logdet + base) = make_float4(lv[0], lv[1], lv[2], lv[3]);
    }
}

extern "C" void kernel_launch(void* const* d_in, const int* in_sizes, int n_in,
                              void* d_out, int out_size, void* d_ws, size_t ws_size,
                              hipStream_t stream) {
    const float* cond = (const float*)d_in[0];
    const float* y    = (const float*)d_in[1];
    const float* W1   = (const float*)d_in[2];
    const float* b1   = (const float*)d_in[3];
    const float* W2   = (const float*)d_in[4];
    const float* b2   = (const float*)d_in[5];
    const float* W3   = (const float*)d_in[6];
    const float* b3   = (const float*)d_in[7];

    float* out    = (float*)d_out;
    float* logdet = out + (size_t)NROW * NCOL;

    fused_spline_flow_kernel<<<NROW/NR, 256, 0, stream>>>(
        cond, y, W1, b1, W2, b2, W3, b3, out, logdet);
}

// Round 5
// 38.025 us; speedup vs baseline: 2.2587x; 1.1386x over previous
//
#include <hip/hip_runtime.h>
#include <math.h>

namespace {
constexpr int KB    = 16;        // spline bins
constexpr int OUTP  = 3*KB + 1;  // 49
constexpr int CDIM  = 64;
constexpr int HDIM  = 256;
constexpr int NCOL  = 1024;
constexpr int NROW  = 4096;
constexpr float BOUNDF = 5.0f;
constexpr float MBW_ = 0.001f;
constexpr float MBH_ = 0.001f;
constexpr float MD_  = 0.001f;
constexpr int PSTR = 51;  // 17 cumw | 17 cumh | 17 deriv
constexpr int NR   = 8;   // rows per block (MLP)
}

// ---------------------------------------------------------------------------
// Kernel A: MLP -> spline params. 512 blocks x 4 waves, split-K (wave owns a
// K-slice; lane owns 4 consecutive cols -> coalesced float4 W loads, W read
// exactly once per block; register prefetch hides L2 latency). Cross-wave
// partials via ps[4][NR][256] (b128 writes / b32 reads, conflict-free).
// ---------------------------------------------------------------------------
__global__ __launch_bounds__(256) void mlp_params_kernel(
    const float* __restrict__ cond,
    const float* __restrict__ W1, const float* __restrict__ b1,
    const float* __restrict__ W2, const float* __restrict__ b2,
    const float* __restrict__ W3, const float* __restrict__ b3,
    float* __restrict__ params)
{
    __shared__ float cond_s[NR][CDIM];       //  2   KB
    __shared__ float ps[4][NR][HDIM];        // 32   KB
    __shared__ float h_s[NR][HDIM];          //  8   KB (h1 then h2)
    __shared__ float p_s[NR][OUTP];          //  1.6 KB
    __shared__ float prm_s[NR][PSTR];        //  1.6 KB

    const int tid  = threadIdx.x;
    const int lane = tid & 63;
    const int wid  = tid >> 6;
    const int row0 = blockIdx.x * NR;

    if (tid < NR*CDIM/4)
        *((float4*)&cond_s[0][0] + tid) = *((const float4*)(cond + (size_t)row0*CDIM) + tid);
    __syncthreads();

    // ---- layer 1: wave owns k in [16w, 16w+16)
    {
        float acc[NR][4];
        #pragma unroll
        for (int r = 0; r < NR; ++r)
            #pragma unroll
            for (int c = 0; c < 4; ++c) acc[r][c] = 0.f;

        #pragma unroll
        for (int kg = 0; kg < 4; ++kg) {
            const int k0 = 16*wid + 4*kg;
            float4 wv[4];
            #pragma unroll
            for (int kk = 0; kk < 4; ++kk)
                wv[kk] = *(const float4*)(W1 + (size_t)(k0+kk)*HDIM + 4*lane);
            #pragma unroll
            for (int r = 0; r < NR; ++r) {
                const float4 cv4 = *(const float4*)&cond_s[r][k0];
                const float cv[4] = {cv4.x, cv4.y, cv4.z, cv4.w};
                const float wf[4][4] = {{wv[0].x,wv[0].y,wv[0].z,wv[0].w},
                                        {wv[1].x,wv[1].y,wv[1].z,wv[1].w},
                                        {wv[2].x,wv[2].y,wv[2].z,wv[2].w},
                                        {wv[3].x,wv[3].y,wv[3].z,wv[3].w}};
                #pragma unroll
                for (int kk = 0; kk < 4; ++kk)
                    #pragma unroll
                    for (int c = 0; c < 4; ++c)
                        acc[r][c] = fmaf(cv[kk], wf[kk][c], acc[r][c]);
            }
        }
        #pragma unroll
        for (int r = 0; r < NR; ++r)
            *(float4*)&ps[wid][r][4*lane] = make_float4(acc[r][0], acc[r][1], acc[r][2], acc[r][3]);
    }
    __syncthreads();
    {
        const float bb = b1[tid];
        #pragma unroll
        for (int r = 0; r < NR; ++r)
            h_s[r][tid] = fmaxf(ps[0][r][tid] + ps[1][r][tid] + ps[2][r][tid] + ps[3][r][tid] + bb, 0.f);
    }
    __syncthreads();

    // ---- layer 2: wave owns k in [64w, 64w+64); register-prefetched W tiles
    {
        float acc[NR][4];
        #pragma unroll
        for (int r = 0; r < NR; ++r)
            #pragma unroll
            for (int c = 0; c < 4; ++c) acc[r][c] = 0.f;

        float4 wn[4];
        #pragma unroll
        for (int kk = 0; kk < 4; ++kk)
            wn[kk] = *(const float4*)(W2 + (size_t)(64*wid+kk)*HDIM + 4*lane);

        #pragma unroll 2
        for (int kg = 0; kg < 16; ++kg) {
            const int k0 = 64*wid + 4*kg;
            float4 wv[4];
            #pragma unroll
            for (int kk = 0; kk < 4; ++kk) wv[kk] = wn[kk];
            if (kg < 15) {
                #pragma unroll
                for (int kk = 0; kk < 4; ++kk)
                    wn[kk] = *(const float4*)(W2 + (size_t)(k0+4+kk)*HDIM + 4*lane);
            }
            #pragma unroll
            for (int r = 0; r < NR; ++r) {
                const float4 hv4 = *(const float4*)&h_s[r][k0];
                const float hv[4] = {hv4.x, hv4.y, hv4.z, hv4.w};
                const float wf[4][4] = {{wv[0].x,wv[0].y,wv[0].z,wv[0].w},
                                        {wv[1].x,wv[1].y,wv[1].z,wv[1].w},
                                        {wv[2].x,wv[2].y,wv[2].z,wv[2].w},
                                        {wv[3].x,wv[3].y,wv[3].z,wv[3].w}};
                #pragma unroll
                for (int kk = 0; kk < 4; ++kk)
                    #pragma unroll
                    for (int c = 0; c < 4; ++c)
                        acc[r][c] = fmaf(hv[kk], wf[kk][c], acc[r][c]);
            }
        }
        #pragma unroll
        for (int r = 0; r < NR; ++r)
            *(float4*)&ps[wid][r][4*lane] = make_float4(acc[r][0], acc[r][1], acc[r][2], acc[r][3]);
    }
    __syncthreads();
    {
        const float bb = b2[tid];
        #pragma unroll
        for (int r = 0; r < NR; ++r)
            h_s[r][tid] = fmaxf(ps[0][r][tid] + ps[1][r][tid] + ps[2][r][tid] + ps[3][r][tid] + bb, 0.f);
    }
    __syncthreads();

    // ---- layer 3: lane = output unit, wave owns k-slice
    {
        const int  o   = lane;
        const bool act = (o < OUTP);
        float acc[NR];
        #pragma unroll
        for (int r = 0; r < NR; ++r) acc[r] = 0.f;

        #pragma unroll 4
        for (int kg = 0; kg < 16; ++kg) {
            const int k0 = 64*wid + 4*kg;
            float wv[4];
            #pragma unroll
            for (int kk = 0; kk < 4; ++kk)
                wv[kk] = act ? W3[(size_t)(k0+kk)*OUTP + o] : 0.f;
            #pragma unroll
            for (int r = 0; r < NR; ++r) {
                const float4 hv = *(const float4*)&h_s[r][k0];
                acc[r] = fmaf(hv.x, wv[0], acc[r]);
                acc[r] = fmaf(hv.y, wv[1], acc[r]);
                acc[r] = fmaf(hv.z, wv[2], acc[r]);
                acc[r] = fmaf(hv.w, wv[3], acc[r]);
            }
        }
        if (act) {
            #pragma unroll
            for (int r = 0; r < NR; ++r) ps[wid][r][o] = acc[r];
        }
    }
    __syncthreads();
    for (int t = tid; t < NR*OUTP; t += 256) {
        const int r = t / OUTP;
        const int o = t - r*OUTP;
        p_s[r][o] = ps[0][r][o] + ps[1][r][o] + ps[2][r][o] + ps[3][r][o] + b3[o];
    }
    __syncthreads();

    // ---- softmax+cumsum (widths, heights) and softplus (derivs)
    if (tid < NR*3) {
        const int r   = tid / 3;
        const int seg = tid - 3*r;
        if (seg < 2) {
            const int   off   = (seg == 0) ? 0 : KB;
            const int   cbase = (seg == 0) ? 0 : 17;
            const float mb    = (seg == 0) ? MBW_ : MBH_;
            float m = -1e30f;
            #pragma unroll
            for (int i = 0; i < KB; ++i) m = fmaxf(m, p_s[r][off+i]);
            float e[KB];
            float s = 0.f;
            #pragma unroll
            for (int i = 0; i < KB; ++i) { e[i] = __expf(p_s[r][off+i] - m); s += e[i]; }
            const float span = (2.f*BOUNDF - (float)KB*mb) / s;
            float c = -BOUNDF;
            prm_s[r][cbase] = c;
            #pragma unroll
            for (int i = 0; i < KB; ++i) {
                c += mb + span*e[i];
                prm_s[r][cbase + 1 + i] = c;
            }
        } else {
            #pragma unroll
            for (int i = 0; i < KB+1; ++i) {
                const float x  = p_s[r][2*KB + i];
                const float sp = (x > 20.f) ? x : __logf(1.f + __expf(x));
                prm_s[r][34 + i] = MD_ + sp;
            }
        }
    }
    __syncthreads();

    for (int i = tid; i < NR*PSTR; i += 256)
        params[(size_t)row0*PSTR + i] = (&prm_s[0][0])[i];
}

// ---------------------------------------------------------------------------
// Kernel B: spline application. 4096 blocks (1 row each, ~1.3 KB LDS ->
// 8 blocks/CU resident). Packed 32B bin records: 1 ds_read_b128 + 1
// ds_read_b64 per element; single fast log for logdet.
// ---------------------------------------------------------------------------
__global__ __launch_bounds__(256) void spline_kernel(
    const float* __restrict__ y,
    const float* __restrict__ params,
    float* __restrict__ out,
    float* __restrict__ logdet)
{
    __shared__ float prm[PSTR];
    __shared__ float rec[KB][8];
    __shared__ float scan_s[KB];

    const int b   = blockIdx.x;
    const int tid = threadIdx.x;
    if (tid < PSTR) prm[tid] = params[(size_t)b*PSTR + tid];
    __syncthreads();
    if (tid < KB) {
        const int k = tid;
        rec[k][0] = prm[k];        rec[k][1] = prm[k+1];
        rec[k][2] = prm[17+k];     rec[k][3] = prm[17+k+1];
        rec[k][4] = prm[34+k];     rec[k][5] = prm[34+k+1];
        rec[k][6] = 0.f;           rec[k][7] = 0.f;
        scan_s[k] = prm[k+1];      // thresholds cumw[1..16]
    }
    __syncthreads();

    float cw[KB];
    #pragma unroll
    for (int q = 0; q < 4; ++q) {
        const float4 t4 = *(const float4*)&scan_s[4*q];   // uniform broadcast
        cw[4*q+0] = t4.x; cw[4*q+1] = t4.y; cw[4*q+2] = t4.z; cw[4*q+3] = t4.w;
    }

    const size_t base = (size_t)b * NCOL + 4*tid;
    const float4 yv   = *(const float4*)(y + base);
    const float  yy[4] = {yv.x, yv.y, yv.z, yv.w};
    float ov[4], lv[4];

    #pragma unroll
    for (int i = 0; i < 4; ++i) {
        const float yi = yy[i];
        const bool outside = (yi < -BOUNDF) || (yi > BOUNDF);
        const float xc = fminf(fmaxf(yi, -BOUNDF), BOUNDF);
        int bin = 0;
        #pragma unroll
        for (int k = 0; k < KB; ++k) bin += (xc >= cw[k]) ? 1 : 0;
        bin = min(bin, KB-1);

        const float4 lo = *(const float4*)&rec[bin][0];   // ds_read_b128
        const float2 hi = *(const float2*)&rec[bin][4];   // ds_read_b64
        const float w  = lo.y - lo.x;
        const float hh = lo.w - lo.z;
        const float d0 = hi.x, d1 = hi.y;

        const float inv_w = __fdividef(1.f, w);
        const float delta = hh * inv_w;
        const float theta = (xc - lo.x) * inv_w;
        const float omt   = 1.f - theta;
        const float tt    = theta * theta;
        const float tomt  = theta * omt;
        const float num   = hh * (delta*tt + d0*tomt);
        const float den   = delta + (d0 + d1 - 2.f*delta)*tomt;
        const float o     = lo.z + __fdividef(num, den);
        const float der_num = fmaxf(delta*delta*(d1*tt + 2.f*delta*tomt + d0*omt*omt), 1e-12f);
        const float der_den = fmaxf(den*den, 1e-12f);
        const float ld      = __logf(__fdividef(der_num, der_den));

        ov[i] = outside ? yi : o;
        lv[i] = outside ? 0.f : ld;
    }

    *(float4*)(out + base)    = make_float4(ov[0], ov[1], ov[2], ov[3]);
    *(float4*)(logdet + base) = make_float4(lv[0], lv[1], lv[2], lv[3]);
}

extern "C" void kernel_launch(void* const* d_in, const int* in_sizes, int n_in,
                              void* d_out, int out_size, void* d_ws, size_t ws_size,
                              hipStream_t stream) {
    const float* cond = (const float*)d_in[0];
    const float* y    = (const float*)d_in[1];
    const float* W1   = (const float*)d_in[2];
    const float* b1   = (const float*)d_in[3];
    const float* W2   = (const float*)d_in[4];
    const float* b2   = (const float*)d_in[5];
    const float* W3   = (const float*)d_in[6];
    const float* b3   = (const float*)d_in[7];

    float* out    = (float*)d_out;
    float* logdet = out + (size_t)NROW * NCOL;
    float* params = (float*)d_ws;   // 4096 * 51 floats = 0.84 MB

    mlp_params_kernel<<<NROW/NR, 256, 0, stream>>>(cond, W1, b1, W2, b2, W3, b3, params);
    spline_kernel<<<NROW, 256, 0, stream>>>(y, params, out, logdet);
}